// Round 13
// baseline (335.604 us; speedup 1.0000x reference)
//
#include <hip/hip_runtime.h>
#include <cstdint>
#include <cstddef>

#define NN 30000
#define DEG 32
#define NEO 16
#define NROWS (NN * DEG)    /* 960000 */

typedef __attribute__((ext_vector_type(8))) short bf16x8;
typedef __attribute__((ext_vector_type(4))) float f32x4;
typedef __attribute__((ext_vector_type(4))) unsigned u32x4;

__device__ __forceinline__ short f2bf(float f) {   // RNE — weights only
    union { float f; unsigned u; } v; v.f = f;
    unsigned r = (v.u + 0x7FFFu + ((v.u >> 16) & 1u)) >> 16;
    return (short)r;
}

// Truncating pair-pack (2 VALU ops), proven: absmax 0.0625 vs threshold 599.
__device__ __forceinline__ unsigned pktr(float a, float b) {
    unsigned ua = __builtin_bit_cast(unsigned, a);
    unsigned ub = __builtin_bit_cast(unsigned, b);
    return (ua >> 16) | (ub & 0xFFFF0000u);
}

__device__ __forceinline__ bf16x8 pack2(f32x4 x, f32x4 y) {
    u32x4 d;
    d[0] = pktr(x[0], x[1]); d[1] = pktr(x[2], x[3]);
    d[2] = pktr(y[0], y[1]); d[3] = pktr(y[2], y[3]);
    return __builtin_bit_cast(bf16x8, d);
}

__device__ __forceinline__ f32x4 relu4(f32x4 v) {
    f32x4 r;
    r[0] = fmaxf(v[0], 0.f); r[1] = fmaxf(v[1], 0.f);
    r[2] = fmaxf(v[2], 0.f); r[3] = fmaxf(v[3], 0.f);
    return r;
}

// ---------------- weight fragment prep (+ stats zeroing fused) ----------------
// kappa(s,lhi,i) = 16*(2*s + (i>>2)) + 4*lhi + (i&3)
// frag f: [0,4): layer1 Wedge(16x64), K padded to 32, k==16 row = bedge
//         [4,20): layer2 w1(64x128) A-frag, nt=(f-4)>>1, s=(f-4)&1, k=kappa
//         [20,36): layer3 w2(128x64) B-frag, t=(f-20)>>2, s=(f-20)&3, k=kappa
__global__ __launch_bounds__(64) void k_wprep(
    const float* __restrict__ Wedge, const float* __restrict__ bedge,
    const float* __restrict__ w1, const float* __restrict__ w2,
    unsigned short* __restrict__ wfrag, float* __restrict__ gstats)
{
    int f = blockIdx.x;
    int l = threadIdx.x;
    if (f == 0) { gstats[l] = 0.0f; gstats[l + 64] = 0.0f; }  // gsum+gsq
    int lhi = l >> 4, llo = l & 15;
    unsigned short out[8];
    #pragma unroll
    for (int i = 0; i < 8; ++i) {
        int k = lhi * 8 + i;
        float val;
        if (f < 4) {
            int col = f * 16 + llo;
            if (k < 16)       val = Wedge[k * 64 + col];
            else if (k == 16) val = bedge[col];
            else              val = 0.0f;
        } else if (f < 20) {
            int idx = f - 4; int nt = idx >> 1, s = idx & 1;
            int kap = 16 * (2 * s + (i >> 2)) + 4 * lhi + (i & 3);
            val = w1[kap * 128 + nt * 16 + llo];
        } else {
            int idx = f - 20; int t = idx >> 2, s = idx & 3;
            int kap = 16 * (2 * s + (i >> 2)) + 4 * lhi + (i & 3);
            val = w2[kap * 64 + t * 16 + llo];
        }
        out[i] = (unsigned short)f2bf(val);
    }
    #pragma unroll
    for (int i = 0; i < 8; ++i) wfrag[((size_t)f * 64 + l) * 8 + i] = out[i];
}

// ---------------- x_out: h = x@Wh+bh ; pe chain (30000 rows, small) ----------------
__global__ __launch_bounds__(256) void k_xout(
    const float* __restrict__ x, const float* __restrict__ rrwp,
    const float* __restrict__ Wh, const float* __restrict__ bh,
    const float* __restrict__ Wn, const float* __restrict__ bnb,
    const float* __restrict__ pw1, const float* __restrict__ pb1,
    const float* __restrict__ pw2, const float* __restrict__ pb2,
    float* __restrict__ out)
{
    int r = blockIdx.x * 256 + threadIdx.x;
    if (r >= NN) return;
    float xv[16], rv[16];
    {
        const float4* p = (const float4*)(x + (size_t)r * 16);
        float4 a = p[0], b = p[1], c = p[2], d = p[3];
        xv[0]=a.x; xv[1]=a.y; xv[2]=a.z; xv[3]=a.w;
        xv[4]=b.x; xv[5]=b.y; xv[6]=b.z; xv[7]=b.w;
        xv[8]=c.x; xv[9]=c.y; xv[10]=c.z; xv[11]=c.w;
        xv[12]=d.x; xv[13]=d.y; xv[14]=d.z; xv[15]=d.w;
    }
    {
        const float4* p = (const float4*)(rrwp + (size_t)r * 16);
        float4 a = p[0], b = p[1], c = p[2], d = p[3];
        rv[0]=a.x; rv[1]=a.y; rv[2]=a.z; rv[3]=a.w;
        rv[4]=b.x; rv[5]=b.y; rv[6]=b.z; rv[7]=b.w;
        rv[8]=c.x; rv[9]=c.y; rv[10]=c.z; rv[11]=c.w;
        rv[12]=d.x; rv[13]=d.y; rv[14]=d.z; rv[15]=d.w;
    }
    float* orow = out + (size_t)r * 128;
    #pragma unroll
    for (int j = 0; j < 96; ++j) {
        float a = bh[j];
        #pragma unroll
        for (int i = 0; i < 16; ++i) a = fmaf(xv[i], Wh[i * 96 + j], a);
        orow[j] = a;
    }
    float p0[32];
    #pragma unroll
    for (int j = 0; j < 32; ++j) {
        float a = bnb[j];
        #pragma unroll
        for (int i = 0; i < 16; ++i) a = fmaf(rv[i], Wn[i * 32 + j], a);
        p0[j] = a;
    }
    float p1[64];
    #pragma unroll
    for (int j = 0; j < 64; ++j) {
        float a = pb1[j];
        #pragma unroll
        for (int i = 0; i < 32; ++i) a = fmaf(p0[i], pw1[i * 64 + j], a);
        p1[j] = fmaxf(a, 0.0f);
    }
    #pragma unroll
    for (int j = 0; j < 32; ++j) {
        float a = pb2[j];
        #pragma unroll
        for (int i = 0; i < 64; ++i) a = fmaf(p1[i], pw2[i * 32 + j], a);
        orow[96 + j] = fmaxf(a, 0.0f);
    }
}

// ---------------- rank / permutation / sidx ----------------
__global__ __launch_bounds__(256) void k_rank(
    const int* __restrict__ cols, int* __restrict__ sortpos,
    float* __restrict__ sidx0, float* __restrict__ sidx1)
{
    int i = blockIdx.x * 256 + threadIdx.x;   // NROWS divisible by 256
    int d = i / NN;
    int r = i - d * NN;
    int c = cols[i];
    int rank = 0;
    #pragma unroll
    for (int d2 = 0; d2 < DEG; ++d2) {
        int c2 = cols[d2 * NN + r];
        rank += (c2 < c) ? 1 : 0;
    }
    int p = r * DEG + rank;
    sortpos[i] = p;
    sidx0[p] = (float)r;
    sidx1[p] = (float)c;
}

// ---------------- fused MFMA MLP: round-10 structure + 2-tile ILP ----------------
// Layers 1-2 transposed orientation (mfma(W, act)); kappa-permuted weights make
// layer transitions pure register repacking. Layer 3 normal orientation.
// Layer-3 weight frags + layer-2 bias in LDS; (256,2).
// NEW: each wave processes TWO independent 16-row tiles per iteration (4 iters),
// giving the scheduler two independent MFMA chains to interleave (latency hiding).
template<int PHASE>
__global__ __launch_bounds__(256, 2) void k_mlp(
    const float* __restrict__ rrwp_val, const float* __restrict__ edge_attr,
    const unsigned short* __restrict__ wfrag,
    const float* __restrict__ b1, const float* __restrict__ b2,
    const float* __restrict__ We, const float* __restrict__ be,
    const int* __restrict__ sortpos,
    const float* __restrict__ gamma, const float* __restrict__ beta,
    float* __restrict__ out_val, float* __restrict__ gsum, float* __restrict__ gsq)
{
    __shared__ __align__(16) unsigned short lwf3[16 * 64 * 8];  // layer-3 frags, 16 KB
    __shared__ __align__(16) float s_b2c[128];                  // b1 C-in, [lhi*8+nt] f32x4
    __shared__ float s_sum[64];
    __shared__ float s_sq[64];

    int tid = threadIdx.x;
    int w = tid >> 6, l = tid & 63;
    int lhi = l >> 4, llo = l & 15;

    // stage layer-3 weight frags (frags 20..35 of wfrag) into LDS, coalesced
    {
        const float4* s = (const float4*)(wfrag + (size_t)20 * 64 * 8);
        float4* dst = (float4*)lwf3;
        #pragma unroll
        for (int k = 0; k < 4; ++k) dst[tid + k * 256] = s[tid + k * 256];
    }
    if (tid < 32) {
        int lh = tid >> 3, nt = tid & 7;
        ((f32x4*)s_b2c)[tid] = *(const f32x4*)(b1 + nt * 16 + 4 * lh);
    }
    if (PHASE == 0) {
        if (tid < 64) { s_sum[tid] = 0.0f; s_sq[tid] = 0.0f; }
    }
    __syncthreads();

    // layer-3 frag accessor: byte addr = f*1024 + l*16 — conflict-free b128
    const unsigned short* wl3 = lwf3 + (size_t)l * 8;
    #define WF3(f) (*(const bf16x8*)(wl3 + (f) * 512))

    // persistent layer-1/2 weight fragments (80 VGPR)
    bf16x8 wf[20];
    #pragma unroll
    for (int f = 0; f < 20; ++f)
        wf[f] = *(const bf16x8*)(wfrag + ((size_t)f * 64 + l) * 8);

    // epilogue constants (feature = t*16 + llo); BN scale/shift derived inline (phase 1)
    float bias3[4], weS[4], beS[4], bnsc[4], bnsh[4];
    #pragma unroll
    for (int t = 0; t < 4; ++t) {
        int fidx = t * 16 + llo;
        bias3[t] = b2[fidx];
        weS[t] = We[fidx];
        beS[t] = be[fidx];
        if (PHASE == 1) {
            const float inv = 1.0f / (float)NROWS;
            float mu  = gsum[fidx] * inv;
            float var = gsq[fidx] * inv - mu * mu;
            float sc  = rsqrtf(var + 1e-5f) * gamma[fidx];
            bnsc[t] = sc;
            bnsh[t] = beta[fidx] - mu * sc;
        } else { bnsc[t] = 0.0f; bnsh[t] = 0.0f; }
    }
    float ssum[4] = {0.f, 0.f, 0.f, 0.f};
    float ssq[4]  = {0.f, 0.f, 0.f, 0.f};

    #pragma unroll 1
    for (int it = 0; it < 4; ++it) {
        // two independent 16-row tiles per iteration
        int tb0 = blockIdx.x * 512 + it * 128 + w * 16;
        int tb[2] = { tb0, tb0 + 64 };

        // a1 for both tiles (X as B-frag): lane holds row llo, k=lhi*8+i; K-pad k==16 -> 1.0
        bf16x8 a1[2];
        #pragma unroll
        for (int p = 0; p < 2; ++p) {
            const float4* src = (const float4*)(rrwp_val + (size_t)(tb[p] + llo) * 16 + (size_t)(lhi & 1) * 8);
            float4 u0 = src[0], u1 = src[1];
            unsigned d0 = pktr(u0.x, u0.y), d1 = pktr(u0.z, u0.w);
            unsigned d2 = pktr(u1.x, u1.y), d3 = pktr(u1.z, u1.w);
            if (lhi >= 2) { d0 = (lhi == 2) ? 0x3F80u : 0u; d1 = 0u; d2 = 0u; d3 = 0u; }
            u32x4 a1d = {d0, d1, d2, d3};
            a1[p] = __builtin_bit_cast(bf16x8, a1d);
        }

        // layer 1 (transposed), both tiles
        f32x4 acc1[2][4];
        #pragma unroll
        for (int p = 0; p < 2; ++p)
            #pragma unroll
            for (int t = 0; t < 4; ++t) {
                f32x4 z = {0.f, 0.f, 0.f, 0.f};
                acc1[p][t] = __builtin_amdgcn_mfma_f32_16x16x32_bf16(wf[t], a1[p], z, 0, 0, 0);
            }

        // pack a2; layer 2 (transposed) in halves; relu+pack a3 — both tiles
        bf16x8 a2[2][2];
        #pragma unroll
        for (int p = 0; p < 2; ++p) {
            a2[p][0] = pack2(acc1[p][0], acc1[p][1]);
            a2[p][1] = pack2(acc1[p][2], acc1[p][3]);
        }
        bf16x8 a3[2][4];
        #pragma unroll
        for (int h = 0; h < 2; ++h)
            #pragma unroll
            for (int p = 0; p < 2; ++p) {
                f32x4 acc2[4];
                #pragma unroll
                for (int q = 0; q < 4; ++q) {
                    int nt = h * 4 + q;
                    f32x4 c2 = ((const f32x4*)s_b2c)[lhi * 8 + nt];
                    acc2[q] = __builtin_amdgcn_mfma_f32_16x16x32_bf16(wf[4 + nt * 2 + 0], a2[p][0], c2, 0, 0, 0);
                    acc2[q] = __builtin_amdgcn_mfma_f32_16x16x32_bf16(wf[4 + nt * 2 + 1], a2[p][1], acc2[q], 0, 0, 0);
                }
                a3[p][2 * h]     = pack2(relu4(acc2[0]), relu4(acc2[1]));
                a3[p][2 * h + 1] = pack2(relu4(acc2[2]), relu4(acc2[3]));
            }

        // layer 3 (normal orientation), weights from LDS, both tiles
        f32x4 acc3[2][4];
        #pragma unroll
        for (int t = 0; t < 4; ++t)
            #pragma unroll
            for (int p = 0; p < 2; ++p) {
                f32x4 c3 = {bias3[t], bias3[t], bias3[t], bias3[t]};
                acc3[p][t] = __builtin_amdgcn_mfma_f32_16x16x32_bf16(a3[p][0], WF3(t * 4 + 0), c3, 0, 0, 0);
                acc3[p][t] = __builtin_amdgcn_mfma_f32_16x16x32_bf16(a3[p][1], WF3(t * 4 + 1), acc3[p][t], 0, 0, 0);
                acc3[p][t] = __builtin_amdgcn_mfma_f32_16x16x32_bf16(a3[p][2], WF3(t * 4 + 2), acc3[p][t], 0, 0, 0);
                acc3[p][t] = __builtin_amdgcn_mfma_f32_16x16x32_bf16(a3[p][3], WF3(t * 4 + 3), acc3[p][t], 0, 0, 0);
            }

        // epilogue for both tiles: relu + edge add (+ BN apply / stats)
        #pragma unroll
        for (int p = 0; p < 2; ++p) {
            int d = tb[p] / NN;              // tile never straddles d (30000 % 16 == 0)
            int rbase = tb[p] - d * NN;
            bool edged = (d >= 1 && d <= NEO);
            float ev[4]; int pp[4];
            #pragma unroll
            for (int r = 0; r < 4; ++r) {
                int row = lhi * 4 + r;
                ev[r] = edged ? edge_attr[(size_t)(d - 1) * NN + rbase + row] : 0.0f;
                pp[r] = (PHASE == 1) ? sortpos[tb[p] + row] : 0;
            }
            #pragma unroll
            for (int t = 0; t < 4; ++t)
                #pragma unroll
                for (int r = 0; r < 4; ++r) {
                    float v = fmaxf(acc3[p][t][r], 0.0f);
                    if (edged) v = fmaf(ev[r], weS[t], v + beS[t]);
                    if (PHASE == 0) {
                        ssum[t] += v;
                        ssq[t]   = fmaf(v, v, ssq[t]);
                    } else {
                        out_val[(size_t)pp[r] * 64 + t * 16 + llo] = fmaf(v, bnsc[t], bnsh[t]);
                    }
                }
        }
    }
    #undef WF3

    if (PHASE == 0) {
        __syncthreads();
        #pragma unroll
        for (int t = 0; t < 4; ++t) {
            float s = ssum[t], q = ssq[t];
            s += __shfl_xor(s, 16); q += __shfl_xor(q, 16);
            s += __shfl_xor(s, 32); q += __shfl_xor(q, 32);
            if (lhi == 0) { atomicAdd(&s_sum[t * 16 + llo], s); atomicAdd(&s_sq[t * 16 + llo], q); }
        }
        __syncthreads();
        if (tid < 64)       atomicAdd(&gsum[tid], s_sum[tid]);
        else if (tid < 128) atomicAdd(&gsq[tid - 64], s_sq[tid - 64]);
    }
}

extern "C" void kernel_launch(void* const* d_in, const int* in_sizes, int n_in,
                              void* d_out, int out_size, void* d_ws, size_t ws_size,
                              hipStream_t stream)
{
    const float* x         = (const float*)d_in[0];
    const float* edge_attr = (const float*)d_in[1];
    const float* rrwp      = (const float*)d_in[2];
    const float* rrwp_val  = (const float*)d_in[3];
    // d_in[4] = edge_index (unused: edges are exactly offset slots 1..16)
    const int*   rrwp_idx  = (const int*)d_in[5];
    const float* Wh    = (const float*)d_in[6];
    const float* bh    = (const float*)d_in[7];
    const float* We    = (const float*)d_in[8];
    const float* be    = (const float*)d_in[9];
    const float* Wn    = (const float*)d_in[10];
    const float* bnb   = (const float*)d_in[11];
    const float* pw1   = (const float*)d_in[12];
    const float* pb1   = (const float*)d_in[13];
    const float* pw2   = (const float*)d_in[14];
    const float* pb2   = (const float*)d_in[15];
    const float* Wedge = (const float*)d_in[16];
    const float* bedge = (const float*)d_in[17];
    const float* ew1   = (const float*)d_in[18];
    const float* eb1   = (const float*)d_in[19];
    const float* ew2   = (const float*)d_in[20];
    const float* eb2   = (const float*)d_in[21];
    const float* gamma = (const float*)d_in[22];
    const float* beta  = (const float*)d_in[23];

    float* out       = (float*)d_out;
    float* out_xout  = out;                              // NN*128
    float* out_sidx0 = out + (size_t)NN * 128;           // NROWS
    float* out_sidx1 = out_sidx0 + NROWS;                // NROWS
    float* out_val   = out_sidx1 + NROWS;                // NROWS*64

    float* ws    = (float*)d_ws;
    float* gsum  = ws;          // 64
    float* gsq   = ws + 64;     // 64
    int*   sortpos = (int*)(ws + 256);                   // NROWS ints
    unsigned short* wfrag = (unsigned short*)(ws + 256 + NROWS);  // 36*64*8 bf16, 16B-aligned

    const int* cols = rrwp_idx + NROWS;  // rrwp_idx[1]

    k_wprep<<<36, 64, 0, stream>>>(Wedge, bedge, ew1, ew2, wfrag, gsum);
    k_xout<<<(NN + 255) / 256, 256, 0, stream>>>(x, rrwp, Wh, bh, Wn, bnb, pw1, pb1, pw2, pb2, out_xout);
    k_rank<<<NROWS / 256, 256, 0, stream>>>(cols, sortpos, out_sidx0, out_sidx1);
    k_mlp<0><<<1875, 256, 0, stream>>>(rrwp_val, edge_attr, wfrag, eb1, eb2, We, be,
                                       sortpos, gamma, beta, out_val, gsum, gsq);
    k_mlp<1><<<1875, 256, 0, stream>>>(rrwp_val, edge_attr, wfrag, eb1, eb2, We, be,
                                       sortpos, gamma, beta, out_val, gsum, gsq);
}

// Round 14
// 203.601 us; speedup vs baseline: 1.6483x; 1.6483x over previous
//
#include <hip/hip_runtime.h>
#include <cstdint>
#include <cstddef>

#define NN 30000
#define DEG 32
#define NEO 16
#define NROWS (NN * DEG)    /* 960000 */

typedef __attribute__((ext_vector_type(8))) short bf16x8;
typedef __attribute__((ext_vector_type(4))) float f32x4;
typedef __attribute__((ext_vector_type(4))) unsigned u32x4;

__device__ __forceinline__ short f2bf(float f) {   // RNE — weights only
    union { float f; unsigned u; } v; v.f = f;
    unsigned r = (v.u + 0x7FFFu + ((v.u >> 16) & 1u)) >> 16;
    return (short)r;
}

// Truncating pair-pack (2 VALU ops), proven: absmax 0.0625 vs threshold 599.
__device__ __forceinline__ unsigned pktr(float a, float b) {
    unsigned ua = __builtin_bit_cast(unsigned, a);
    unsigned ub = __builtin_bit_cast(unsigned, b);
    return (ua >> 16) | (ub & 0xFFFF0000u);
}

__device__ __forceinline__ bf16x8 pack2(f32x4 x, f32x4 y) {
    u32x4 d;
    d[0] = pktr(x[0], x[1]); d[1] = pktr(x[2], x[3]);
    d[2] = pktr(y[0], y[1]); d[3] = pktr(y[2], y[3]);
    return __builtin_bit_cast(bf16x8, d);
}

__device__ __forceinline__ f32x4 relu4(f32x4 v) {
    f32x4 r;
    r[0] = fmaxf(v[0], 0.f); r[1] = fmaxf(v[1], 0.f);
    r[2] = fmaxf(v[2], 0.f); r[3] = fmaxf(v[3], 0.f);
    return r;
}

// ---------------- weight fragment prep (+ stats zeroing fused) ----------------
// kappa(s,lhi,i) = 16*(2*s + (i>>2)) + 4*lhi + (i&3)
// frag f: [0,4): layer1 Wedge(16x64), K padded to 32, k==16 row = bedge
//         [4,20): layer2 w1(64x128) A-frag, nt=(f-4)>>1, s=(f-4)&1, k=kappa
//         [20,36): layer3 w2(128x64) B-frag, t=(f-20)>>2, s=(f-20)&3, k=kappa
__global__ __launch_bounds__(64) void k_wprep(
    const float* __restrict__ Wedge, const float* __restrict__ bedge,
    const float* __restrict__ w1, const float* __restrict__ w2,
    unsigned short* __restrict__ wfrag, float* __restrict__ gstats)
{
    int f = blockIdx.x;
    int l = threadIdx.x;
    if (f == 0) { gstats[l] = 0.0f; gstats[l + 64] = 0.0f; }  // gsum+gsq
    int lhi = l >> 4, llo = l & 15;
    unsigned short out[8];
    #pragma unroll
    for (int i = 0; i < 8; ++i) {
        int k = lhi * 8 + i;
        float val;
        if (f < 4) {
            int col = f * 16 + llo;
            if (k < 16)       val = Wedge[k * 64 + col];
            else if (k == 16) val = bedge[col];
            else              val = 0.0f;
        } else if (f < 20) {
            int idx = f - 4; int nt = idx >> 1, s = idx & 1;
            int kap = 16 * (2 * s + (i >> 2)) + 4 * lhi + (i & 3);
            val = w1[kap * 128 + nt * 16 + llo];
        } else {
            int idx = f - 20; int t = idx >> 2, s = idx & 3;
            int kap = 16 * (2 * s + (i >> 2)) + 4 * lhi + (i & 3);
            val = w2[kap * 64 + t * 16 + llo];
        }
        out[i] = (unsigned short)f2bf(val);
    }
    #pragma unroll
    for (int i = 0; i < 8; ++i) wfrag[((size_t)f * 64 + l) * 8 + i] = out[i];
}

// ---------------- x_out: h = x@Wh+bh ; pe chain (30000 rows, small) ----------------
__global__ __launch_bounds__(256) void k_xout(
    const float* __restrict__ x, const float* __restrict__ rrwp,
    const float* __restrict__ Wh, const float* __restrict__ bh,
    const float* __restrict__ Wn, const float* __restrict__ bnb,
    const float* __restrict__ pw1, const float* __restrict__ pb1,
    const float* __restrict__ pw2, const float* __restrict__ pb2,
    float* __restrict__ out)
{
    int r = blockIdx.x * 256 + threadIdx.x;
    if (r >= NN) return;
    float xv[16], rv[16];
    {
        const float4* p = (const float4*)(x + (size_t)r * 16);
        float4 a = p[0], b = p[1], c = p[2], d = p[3];
        xv[0]=a.x; xv[1]=a.y; xv[2]=a.z; xv[3]=a.w;
        xv[4]=b.x; xv[5]=b.y; xv[6]=b.z; xv[7]=b.w;
        xv[8]=c.x; xv[9]=c.y; xv[10]=c.z; xv[11]=c.w;
        xv[12]=d.x; xv[13]=d.y; xv[14]=d.z; xv[15]=d.w;
    }
    {
        const float4* p = (const float4*)(rrwp + (size_t)r * 16);
        float4 a = p[0], b = p[1], c = p[2], d = p[3];
        rv[0]=a.x; rv[1]=a.y; rv[2]=a.z; rv[3]=a.w;
        rv[4]=b.x; rv[5]=b.y; rv[6]=b.z; rv[7]=b.w;
        rv[8]=c.x; rv[9]=c.y; rv[10]=c.z; rv[11]=c.w;
        rv[12]=d.x; rv[13]=d.y; rv[14]=d.z; rv[15]=d.w;
    }
    float* orow = out + (size_t)r * 128;
    #pragma unroll
    for (int j = 0; j < 96; ++j) {
        float a = bh[j];
        #pragma unroll
        for (int i = 0; i < 16; ++i) a = fmaf(xv[i], Wh[i * 96 + j], a);
        orow[j] = a;
    }
    float p0[32];
    #pragma unroll
    for (int j = 0; j < 32; ++j) {
        float a = bnb[j];
        #pragma unroll
        for (int i = 0; i < 16; ++i) a = fmaf(rv[i], Wn[i * 32 + j], a);
        p0[j] = a;
    }
    float p1[64];
    #pragma unroll
    for (int j = 0; j < 64; ++j) {
        float a = pb1[j];
        #pragma unroll
        for (int i = 0; i < 32; ++i) a = fmaf(p0[i], pw1[i * 64 + j], a);
        p1[j] = fmaxf(a, 0.0f);
    }
    #pragma unroll
    for (int j = 0; j < 32; ++j) {
        float a = pb2[j];
        #pragma unroll
        for (int i = 0; i < 64; ++i) a = fmaf(p1[i], pw2[i * 32 + j], a);
        orow[96 + j] = fmaxf(a, 0.0f);
    }
}

// ---------------- rank / permutation / sidx — thread-per-row ----------------
// Thread r loads its 32 cols ONCE (coalesced across lanes), computes all 32
// ranks with static comparisons, writes: sidx0 segment (splat r, float4),
// sortpos (coalesced across lanes), sidx1 (scatter within own 128B window).
__global__ __launch_bounds__(256) void k_rank(
    const int* __restrict__ cols, int* __restrict__ sortpos,
    float* __restrict__ sidx0, float* __restrict__ sidx1)
{
    int r = blockIdx.x * 256 + threadIdx.x;
    if (r >= NN) return;
    int c[DEG];
    #pragma unroll
    for (int d = 0; d < DEG; ++d) c[d] = cols[(size_t)d * NN + r];
    // sidx0 segment: every entry of row-segment r has row index r
    float4 rsplat = { (float)r, (float)r, (float)r, (float)r };
    float4* s0 = (float4*)(sidx0 + (size_t)r * DEG);
    #pragma unroll
    for (int k = 0; k < 8; ++k) s0[k] = rsplat;
    #pragma unroll 4
    for (int d = 0; d < DEG; ++d) {
        int rank = 0;
        #pragma unroll
        for (int k = 0; k < DEG; ++k) rank += (c[k] < c[d]) ? 1 : 0;
        sortpos[(size_t)d * NN + r] = r * DEG + rank;
        sidx1[(size_t)r * DEG + rank] = (float)c[d];
    }
}

// ---------------- fused MFMA MLP: all layer-2/3 weights in LDS ----------------
// Layers 1-2 transposed orientation (mfma(W, act)); kappa-permuted weights make
// layer transitions pure register repacking. Layer 3 normal orientation.
// Register-pressure lever continued (r8->r10 proved it): frags 4..35 (layer 2+3)
// live in LDS (32 KB, conflict-free l*16 ds_read_b128); only layer-1's 4 frags
// stay in registers. (256,2).
template<int PHASE>
__global__ __launch_bounds__(256, 2) void k_mlp(
    const float* __restrict__ rrwp_val, const float* __restrict__ edge_attr,
    const unsigned short* __restrict__ wfrag,
    const float* __restrict__ b1, const float* __restrict__ b2,
    const float* __restrict__ We, const float* __restrict__ be,
    const int* __restrict__ sortpos,
    const float* __restrict__ gamma, const float* __restrict__ beta,
    float* __restrict__ out_val, float* __restrict__ gsum, float* __restrict__ gsq)
{
    __shared__ __align__(16) unsigned short lwf[32 * 64 * 8];   // frags 4..35, 32 KB
    __shared__ __align__(16) float s_b2c[128];                  // b1 C-in, [lhi*8+nt] f32x4
    __shared__ float s_sum[64];
    __shared__ float s_sq[64];

    int tid = threadIdx.x;
    int w = tid >> 6, l = tid & 63;
    int lhi = l >> 4, llo = l & 15;

    // stage frags 4..35 into LDS, coalesced (32 KB = 2048 float4)
    {
        const float4* s = (const float4*)(wfrag + (size_t)4 * 64 * 8);
        float4* dst = (float4*)lwf;
        #pragma unroll
        for (int k = 0; k < 8; ++k) dst[tid + k * 256] = s[tid + k * 256];
    }
    if (tid < 32) {
        int lh = tid >> 3, nt = tid & 7;
        ((f32x4*)s_b2c)[tid] = *(const f32x4*)(b1 + nt * 16 + 4 * lh);
    }
    if (PHASE == 0) {
        if (tid < 64) { s_sum[tid] = 0.0f; s_sq[tid] = 0.0f; }
    }
    __syncthreads();

    // LDS frag accessor: fl = frag index - 4 (0..31); byte addr = fl*1024 + l*16
    const unsigned short* wl = lwf + (size_t)l * 8;
    #define WFL(fl) (*(const bf16x8*)(wl + (fl) * 512))

    // persistent layer-1 weight fragments only (16 VGPR)
    bf16x8 wf1[4];
    #pragma unroll
    for (int f = 0; f < 4; ++f)
        wf1[f] = *(const bf16x8*)(wfrag + ((size_t)f * 64 + l) * 8);

    // epilogue constants (feature = t*16 + llo); BN scale/shift derived inline (phase 1)
    float bias3[4], weS[4], beS[4], bnsc[4], bnsh[4];
    #pragma unroll
    for (int t = 0; t < 4; ++t) {
        int fidx = t * 16 + llo;
        bias3[t] = b2[fidx];
        weS[t] = We[fidx];
        beS[t] = be[fidx];
        if (PHASE == 1) {
            const float inv = 1.0f / (float)NROWS;
            float mu  = gsum[fidx] * inv;
            float var = gsq[fidx] * inv - mu * mu;
            float sc  = rsqrtf(var + 1e-5f) * gamma[fidx];
            bnsc[t] = sc;
            bnsh[t] = beta[fidx] - mu * sc;
        } else { bnsc[t] = 0.0f; bnsh[t] = 0.0f; }
    }
    float ssum[4] = {0.f, 0.f, 0.f, 0.f};
    float ssq[4]  = {0.f, 0.f, 0.f, 0.f};

    #pragma unroll 1
    for (int it = 0; it < 8; ++it) {
        int tb = blockIdx.x * 512 + it * 64 + w * 16;

        // a1 (X as B-frag): lane holds row llo, k = lhi*8+i; K-pad k==16 -> 1.0 bias row
        const float4* src = (const float4*)(rrwp_val + (size_t)(tb + llo) * 16 + (size_t)(lhi & 1) * 8);
        float4 u0 = src[0], u1 = src[1];
        unsigned d0 = pktr(u0.x, u0.y), d1 = pktr(u0.z, u0.w);
        unsigned d2 = pktr(u1.x, u1.y), d3 = pktr(u1.z, u1.w);
        if (lhi >= 2) { d0 = (lhi == 2) ? 0x3F80u : 0u; d1 = 0u; d2 = 0u; d3 = 0u; }
        u32x4 a1d = {d0, d1, d2, d3};
        bf16x8 a1 = __builtin_bit_cast(bf16x8, a1d);

        // layer 1 (transposed): acc1[t][r] = Y1[row llo][feat t*16+4*lhi+r]
        f32x4 acc1[4];
        #pragma unroll
        for (int t = 0; t < 4; ++t) {
            f32x4 z = {0.f, 0.f, 0.f, 0.f};
            acc1[t] = __builtin_amdgcn_mfma_f32_16x16x32_bf16(wf1[t], a1, z, 0, 0, 0);
        }

        // pack a2 (kappa order); layer 2 (transposed, weights from LDS) in halves
        bf16x8 a2[2];
        a2[0] = pack2(acc1[0], acc1[1]);
        a2[1] = pack2(acc1[2], acc1[3]);
        bf16x8 a3[4];
        #pragma unroll
        for (int h = 0; h < 2; ++h) {
            f32x4 acc2[4];
            #pragma unroll
            for (int q = 0; q < 4; ++q) {
                int nt = h * 4 + q;
                f32x4 c2 = ((const f32x4*)s_b2c)[lhi * 8 + nt];
                acc2[q] = __builtin_amdgcn_mfma_f32_16x16x32_bf16(WFL(nt * 2 + 0), a2[0], c2, 0, 0, 0);
                acc2[q] = __builtin_amdgcn_mfma_f32_16x16x32_bf16(WFL(nt * 2 + 1), a2[1], acc2[q], 0, 0, 0);
            }
            a3[2 * h]     = pack2(relu4(acc2[0]), relu4(acc2[1]));
            a3[2 * h + 1] = pack2(relu4(acc2[2]), relu4(acc2[3]));
        }

        // layer 3 (normal orientation), weights from LDS, bias3 via C-in splat
        f32x4 acc3[4];
        #pragma unroll
        for (int t = 0; t < 4; ++t) {
            f32x4 c3 = {bias3[t], bias3[t], bias3[t], bias3[t]};
            acc3[t] = __builtin_amdgcn_mfma_f32_16x16x32_bf16(a3[0], WFL(16 + t * 4 + 0), c3, 0, 0, 0);
            acc3[t] = __builtin_amdgcn_mfma_f32_16x16x32_bf16(a3[1], WFL(16 + t * 4 + 1), acc3[t], 0, 0, 0);
            acc3[t] = __builtin_amdgcn_mfma_f32_16x16x32_bf16(a3[2], WFL(16 + t * 4 + 2), acc3[t], 0, 0, 0);
            acc3[t] = __builtin_amdgcn_mfma_f32_16x16x32_bf16(a3[3], WFL(16 + t * 4 + 3), acc3[t], 0, 0, 0);
        }

        // epilogue: relu + edge add (+ BN apply / stats)
        int d = tb / NN;                 // tile never straddles d (30000 % 16 == 0)
        int rbase = tb - d * NN;
        bool edged = (d >= 1 && d <= NEO);
        float ev[4]; int pp[4];
        #pragma unroll
        for (int r = 0; r < 4; ++r) {
            int row = lhi * 4 + r;
            ev[r] = edged ? edge_attr[(size_t)(d - 1) * NN + rbase + row] : 0.0f;
            pp[r] = (PHASE == 1) ? sortpos[tb + row] : 0;
        }
        #pragma unroll
        for (int t = 0; t < 4; ++t)
            #pragma unroll
            for (int r = 0; r < 4; ++r) {
                float v = fmaxf(acc3[t][r], 0.0f);
                if (edged) v = fmaf(ev[r], weS[t], v + beS[t]);
                if (PHASE == 0) {
                    ssum[t] += v;
                    ssq[t]   = fmaf(v, v, ssq[t]);
                } else {
                    out_val[(size_t)pp[r] * 64 + t * 16 + llo] = fmaf(v, bnsc[t], bnsh[t]);
                }
            }
    }
    #undef WFL

    if (PHASE == 0) {
        __syncthreads();
        #pragma unroll
        for (int t = 0; t < 4; ++t) {
            float s = ssum[t], q = ssq[t];
            s += __shfl_xor(s, 16); q += __shfl_xor(q, 16);
            s += __shfl_xor(s, 32); q += __shfl_xor(q, 32);
            if (lhi == 0) { atomicAdd(&s_sum[t * 16 + llo], s); atomicAdd(&s_sq[t * 16 + llo], q); }
        }
        __syncthreads();
        if (tid < 64)       atomicAdd(&gsum[tid], s_sum[tid]);
        else if (tid < 128) atomicAdd(&gsq[tid - 64], s_sq[tid - 64]);
    }
}

extern "C" void kernel_launch(void* const* d_in, const int* in_sizes, int n_in,
                              void* d_out, int out_size, void* d_ws, size_t ws_size,
                              hipStream_t stream)
{
    const float* x         = (const float*)d_in[0];
    const float* edge_attr = (const float*)d_in[1];
    const float* rrwp      = (const float*)d_in[2];
    const float* rrwp_val  = (const float*)d_in[3];
    // d_in[4] = edge_index (unused: edges are exactly offset slots 1..16)
    const int*   rrwp_idx  = (const int*)d_in[5];
    const float* Wh    = (const float*)d_in[6];
    const float* bh    = (const float*)d_in[7];
    const float* We    = (const float*)d_in[8];
    const float* be    = (const float*)d_in[9];
    const float* Wn    = (const float*)d_in[10];
    const float* bnb   = (const float*)d_in[11];
    const float* pw1   = (const float*)d_in[12];
    const float* pb1   = (const float*)d_in[13];
    const float* pw2   = (const float*)d_in[14];
    const float* pb2   = (const float*)d_in[15];
    const float* Wedge = (const float*)d_in[16];
    const float* bedge = (const float*)d_in[17];
    const float* ew1   = (const float*)d_in[18];
    const float* eb1   = (const float*)d_in[19];
    const float* ew2   = (const float*)d_in[20];
    const float* eb2   = (const float*)d_in[21];
    const float* gamma = (const float*)d_in[22];
    const float* beta  = (const float*)d_in[23];

    float* out       = (float*)d_out;
    float* out_xout  = out;                              // NN*128
    float* out_sidx0 = out + (size_t)NN * 128;           // NROWS
    float* out_sidx1 = out_sidx0 + NROWS;                // NROWS
    float* out_val   = out_sidx1 + NROWS;                // NROWS*64

    float* ws    = (float*)d_ws;
    float* gsum  = ws;          // 64
    float* gsq   = ws + 64;     // 64
    int*   sortpos = (int*)(ws + 256);                   // NROWS ints
    unsigned short* wfrag = (unsigned short*)(ws + 256 + NROWS);  // 36*64*8 bf16, 16B-aligned

    const int* cols = rrwp_idx + NROWS;  // rrwp_idx[1]

    k_wprep<<<36, 64, 0, stream>>>(Wedge, bedge, ew1, ew2, wfrag, gsum);
    k_xout<<<(NN + 255) / 256, 256, 0, stream>>>(x, rrwp, Wh, bh, Wn, bnb, pw1, pb1, pw2, pb2, out_xout);
    k_rank<<<(NN + 255) / 256, 256, 0, stream>>>(cols, sortpos, out_sidx0, out_sidx1);
    k_mlp<0><<<1875, 256, 0, stream>>>(rrwp_val, edge_attr, wfrag, eb1, eb2, We, be,
                                       sortpos, gamma, beta, out_val, gsum, gsq);
    k_mlp<1><<<1875, 256, 0, stream>>>(rrwp_val, edge_attr, wfrag, eb1, eb2, We, be,
                                       sortpos, gamma, beta, out_val, gsum, gsq);
}